// Round 6
// baseline (396.452 us; speedup 1.0000x reference)
//
#include <hip/hip_runtime.h>

typedef __attribute__((ext_vector_type(8))) short short8;
typedef __attribute__((ext_vector_type(4))) float floatx4;
typedef __attribute__((ext_vector_type(16))) float floatx16;
typedef unsigned short ushort_t;

#define S_LEN 4096
#define NH 12
#define DK 64
#define DM 768
#define BQ 128
#define LOG2E 1.4426950408889634f

static __device__ __forceinline__ unsigned short f2bf(float f) {
    unsigned int u = __float_as_uint(f);
    u += 0x7FFFu + ((u >> 16) & 1u);
    return (unsigned short)(u >> 16);
}
static __device__ __forceinline__ unsigned pack2(float a, float b) {
    return (unsigned)f2bf(a) | ((unsigned)f2bf(b) << 16);
}
// fast pack: round-half-up (bias cancels in softmax ratio), 3 VALU ops/pair
static __device__ __forceinline__ unsigned pack2f(float a, float b) {
    unsigned au = __float_as_uint(a) + 0x8000u;
    unsigned bu = __float_as_uint(b) + 0x8000u;
    return (bu & 0xFFFF0000u) | (au >> 16);
}
// async global->LDS, 16B per lane; LDS dest must be wave-uniform base + lane*16
static __device__ __forceinline__ void gld_lds16(const void* g, void* l) {
    __builtin_amdgcn_global_load_lds(
        (__attribute__((address_space(1))) void*)g,
        (__attribute__((address_space(3))) void*)l, 16, 0, 0);
}
union U4S8 { uint4 u; short8 s; };

// ---------------- prep: weight transpose+cast AND q/k/v fp32->bf16 ---------
// blocks [0, 2304): weight transpose tiles; [2304, 2304+9216): cvt chunks
__global__ __launch_bounds__(256)
void prep_kernel(const float* __restrict__ W0, const float* __restrict__ W1,
                 const float* __restrict__ W2, const float* __restrict__ W3,
                 ushort_t* __restrict__ T0, ushort_t* __restrict__ T1,
                 ushort_t* __restrict__ T2, ushort_t* __restrict__ T3,
                 const float* __restrict__ A0, const float* __restrict__ A1,
                 const float* __restrict__ A2, ushort_t* __restrict__ O0,
                 ushort_t* __restrict__ O1, ushort_t* __restrict__ O2) {
    const int bid = blockIdx.x;
    const int t = threadIdx.x;
    if (bid < 2304) {
        __shared__ float tile[32][33];
        const int z = bid / 576, rem = bid % 576;
        const int by = rem / 24, bx = rem % 24;
        const float* W = (z == 0) ? W0 : (z == 1) ? W1 : (z == 2) ? W2 : W3;
        ushort_t* T = (z == 0) ? T0 : (z == 1) ? T1 : (z == 2) ? T2 : T3;
        const int tx = t & 31, ty = t >> 5;
        #pragma unroll
        for (int j = 0; j < 32; j += 8)
            tile[ty + j][tx] = W[(size_t)(by * 32 + ty + j) * DM + bx * 32 + tx];
        __syncthreads();
        #pragma unroll
        for (int j = 0; j < 32; j += 8)
            T[(size_t)(bx * 32 + ty + j) * DM + by * 32 + tx] = f2bf(tile[tx][ty + j]);
    } else {
        const int c = bid - 2304;
        const int z = c / 3072, blk = c % 3072;
        const float* A = (z == 0) ? A0 : (z == 1) ? A1 : A2;
        ushort_t* O = (z == 0) ? O0 : (z == 1) ? O1 : O2;
        const size_t i = ((size_t)blk * 256 + t) * 8;
        const float4 f0 = *(const float4*)(A + i);
        const float4 f1 = *(const float4*)(A + i + 4);
        uint4 o;
        o.x = pack2(f0.x, f0.y);
        o.y = pack2(f0.z, f0.w);
        o.z = pack2(f1.x, f1.y);
        o.w = pack2(f1.z, f1.w);
        *(uint4*)(O + i) = o;
    }
}

// ---------------- V transpose: Vn [bh][s][64] -> Vt [bh][64][s] -------------
__global__ __launch_bounds__(256)
void vtrans_kernel(const ushort_t* __restrict__ Vn, ushort_t* __restrict__ Vt) {
    __shared__ ushort_t tl[64 * 72];
    const int s0 = blockIdx.x * 64;
    const size_t bh = blockIdx.y;
    const int t = threadIdx.x;
    {
        const int r = t >> 2, c0 = (t & 3) * 16;
        const uint4* src = (const uint4*)(Vn + (bh * S_LEN + s0 + r) * DK + c0);
        uint4 a0 = src[0], a1 = src[1];
        uint4* dst = (uint4*)&tl[r * 72 + c0];
        dst[0] = a0;
        dst[1] = a1;
    }
    __syncthreads();
    {
        const int d = t >> 2, c0 = (t & 3) * 16;
        alignas(16) ushort_t tmp[16];
        #pragma unroll
        for (int j = 0; j < 16; ++j) tmp[j] = tl[(c0 + j) * 72 + d];
        uint4* dst = (uint4*)(Vt + (bh * DK + d) * S_LEN + s0 + c0);
        dst[0] = *(const uint4*)&tmp[0];
        dst[1] = *(const uint4*)&tmp[8];
    }
}

// ---------------- GEMM (m97-style): C = A . Wt^T + bias ---------------------
struct GemmArgs {
    const ushort_t* A[3];
    const ushort_t* Wt[3];
    const float* bias[3];
    void* C[3];
    float scale[3];
};

template <int MODE>
__global__ __launch_bounds__(256, 3)
void gemm_kernel(GemmArgs args) {
    __shared__ ushort_t As[128 * 32];
    __shared__ ushort_t Bs[128 * 32];
    const int z = blockIdx.z;
    const ushort_t* A = args.A[z];
    const ushort_t* Wt = args.Wt[z];
    const float* bias = args.bias[z];
    void* Carg = args.C[z];
    const float scale = args.scale[z];

    const int m0 = blockIdx.x * 128;
    const int n0 = blockIdx.y * 128;
    const int t = threadIdx.x;
    const int w = t >> 6, lane = t & 63, l15 = lane & 15, quad = lane >> 4;
    const int rowoff = (w >> 1) * 64, coloff = (w & 1) * 64;
    const int srow = w * 16 + (lane >> 2);
    const int scol = (lane & 3) * 8;

    floatx4 acc[4][4];
    #pragma unroll
    for (int i = 0; i < 4; ++i)
        #pragma unroll
        for (int j = 0; j < 4; ++j) acc[i][j] = (floatx4){0.f, 0.f, 0.f, 0.f};

    for (int kt = 0; kt < DM; kt += 32) {
        __syncthreads();
        #pragma unroll
        for (int j = 0; j < 2; ++j) {
            const int r = j * 64 + srow;
            gld_lds16(A + (size_t)(m0 + r) * DM + kt + scol, &As[r * 32 + scol]);
            gld_lds16(Wt + (size_t)(n0 + r) * DM + kt + scol, &Bs[r * 32 + scol]);
        }
        __asm__ __volatile__("s_waitcnt vmcnt(0)" ::: "memory");
        __syncthreads();
        short8 af[4], bfr[4];
        #pragma unroll
        for (int i = 0; i < 4; ++i)
            af[i] = *(const short8*)&As[(rowoff + 16 * i + l15) * 32 + quad * 8];
        #pragma unroll
        for (int j = 0; j < 4; ++j)
            bfr[j] = *(const short8*)&Bs[(coloff + 16 * j + l15) * 32 + quad * 8];
        #pragma unroll
        for (int i = 0; i < 4; ++i)
            #pragma unroll
            for (int j = 0; j < 4; ++j)
                acc[i][j] = __builtin_amdgcn_mfma_f32_16x16x32_bf16(af[i], bfr[j], acc[i][j], 0, 0, 0);
    }

    #pragma unroll
    for (int i = 0; i < 4; ++i) {
        #pragma unroll
        for (int j = 0; j < 4; ++j) {
            #pragma unroll
            for (int reg = 0; reg < 4; ++reg) {
                const int m = m0 + rowoff + 16 * i + quad * 4 + reg;
                const int n = n0 + coloff + 16 * j + l15;
                const float v2 = (acc[i][j][reg] + bias[n]) * scale;
                if (MODE == 0) {
                    ushort_t* Out = (ushort_t*)Carg;
                    const int b = m >> 12, s = m & 4095, h = n >> 6, d = n & 63;
                    Out[((size_t)((b * NH + h) * S_LEN + s)) * DK + d] = f2bf(v2);
                } else {
                    float* Out = (float*)Carg;
                    Out[(size_t)m * DM + n] = v2;
                }
            }
        }
    }
}

// ---------------- flash attention: register-resident P ----------------------
// Key trick: K rows are staged PERMUTED by sigma (swap bits 2,3 of row index),
// applied to the GLOBAL address. Then the QK^T C-layout row m corresponds to
// kv = sigma(m), which makes each lane's post-exp scores EXACTLY the PV
// B-operand fragments (k = 16ks + 8*half + j) -- P never touches LDS.
// PV computes O^T = V^T(A) x P(B); O^T C-layout has one q per lane, so the
// final 1/l scaling needs no cross-lane ops and X stores are 8B-vectorized.
__global__ __launch_bounds__(256, 3)
void attn_kernel(const ushort_t* __restrict__ Q, const ushort_t* __restrict__ K,
                 const ushort_t* __restrict__ VT, const int* __restrict__ mask,
                 ushort_t* __restrict__ X) {
    __shared__ ushort_t Qs[BQ * DK];
    __shared__ ushort_t Ks0[64 * DK], Ks1[64 * DK];
    __shared__ ushort_t Vs0[64 * DK], Vs1[64 * DK];

    // XCD-locality swizzle: id&7 ~ XCD; each XCD owns 3 (b,h) pairs.
    const int id = blockIdx.x;
    const int per = id >> 3;
    const int bh = (id & 7) * 3 + (per >> 5);
    const int qb = per & 31;
    const int b = bh / NH, h = bh - b * NH;
    const size_t bho = (size_t)bh * S_LEN;
    const ushort_t* Vbase = VT + (size_t)bh * DK * S_LEN;
    const int t = threadIdx.x;
    const int w = t >> 6, lane = t & 63, l31 = lane & 31, half = lane >> 5;
    const int q0 = qb * BQ;
    const int swl = l31 & 7;
    const int frow8 = lane >> 3;
    const int fcc = lane & 7;

    auto sigma = [](int r) { return (r & ~12) | ((r & 4) << 1) | ((r & 8) >> 1); };

    auto fillK = [&](int kv0, ushort_t* Kb) {
        #pragma unroll
        for (int j = 0; j < 2; ++j) {
            const int r = (w * 2 + j) * 8 + frow8;
            const int gr = sigma(r);             // permuted global row
            const int c8 = fcc ^ (r & 7);        // inverse chunk swizzle
            gld_lds16(K + (bho + kv0 + gr) * DK + c8 * 8, &Kb[r * DK + fcc * 8]);
        }
    };
    auto fillV = [&](int kv0, ushort_t* Vb) {
        #pragma unroll
        for (int j = 0; j < 2; ++j) {
            const int r = (w * 2 + j) * 8 + frow8;
            const int c8 = fcc ^ (r & 7);
            gld_lds16(Vbase + (size_t)r * S_LEN + kv0 + c8 * 8, &Vb[r * DK + fcc * 8]);
        }
    };

    // prologue: async tile 0 + Q fill, mask all-ones reduction (barrier)
    fillK(0, Ks0);
    fillV(0, Vs0);
    #pragma unroll
    for (int j = 0; j < 4; ++j) {
        const int r = (w * 4 + j) * 8 + frow8;
        const int c8 = fcc ^ (r & 7);
        gld_lds16(Q + (bho + q0 + r) * DK + c8 * 8, &Qs[r * DK + fcc * 8]);
    }
    int ok = 1;
    {
        const int* mrow = mask + (size_t)b * S_LEN + t * 16;
        #pragma unroll
        for (int i = 0; i < 4; ++i) {
            const int4 mm = *(const int4*)(mrow + i * 4);
            ok &= (mm.x != 0) & (mm.y != 0) & (mm.z != 0) & (mm.w != 0);
        }
    }
    const int allones = __syncthreads_and(ok);

    short8 qf[4];  // Q fragments (B-operand), register-resident
    #pragma unroll
    for (int ks = 0; ks < 4; ++ks) {
        const int c8 = ks * 2 + half;
        qf[ks] = *(const short8*)&Qs[(w * 32 + l31) * DK + ((c8 ^ swl) << 3)];
    }

    floatx16 o[2];
    #pragma unroll
    for (int dt = 0; dt < 2; ++dt)
        #pragma unroll
        for (int r = 0; r < 16; ++r) o[dt][r] = 0.f;
    float l_r = 0.f;

    auto body = [&](int it, const ushort_t* Kc, const ushort_t* Vc,
                    ushort_t* Kn, ushort_t* Vn) {
        __syncthreads();
        if (it + 1 < S_LEN / 64) {
            fillK((it + 1) * 64, Kn);
            fillV((it + 1) * 64, Vn);
        }
        unsigned long long mb = ~0ULL;
        if (!allones) {
            const int mv = mask[(size_t)b * S_LEN + it * 64 + lane];
            mb = __ballot(mv != 0);
        }

        // S^T[m][q], m = sigma(kv): A=K-perm rows (LDS), B=Q (regs)
        floatx16 st[2];
        #pragma unroll
        for (int kt = 0; kt < 2; ++kt) {
            floatx16 s;
            #pragma unroll
            for (int r = 0; r < 16; ++r) s[r] = 0.f;
            #pragma unroll
            for (int ks = 0; ks < 4; ++ks) {
                const int c8 = ks * 2 + half;
                const short8 kf = *(const short8*)&Kc[(kt * 32 + l31) * DK + ((c8 ^ swl) << 3)];
                s = __builtin_amdgcn_mfma_f32_32x32x16_bf16(kf, qf[ks], s, 0, 0, 0);
            }
            st[kt] = s;
        }

        if (mb != ~0ULL) {
            #pragma unroll
            for (int kt = 0; kt < 2; ++kt)
                #pragma unroll
                for (int reg = 0; reg < 16; ++reg) {
                    const int kv = 32 * kt + 8 * half + (reg & 3) +
                                   4 * ((reg >> 2) & 1) + 16 * (reg >> 3);
                    if (!((mb >> kv) & 1)) st[kt][reg] = -3.0e10f;
                }
        }

        // exp2 + partial row-sum + pack into PV B-fragments (pure registers)
        short8 pf[4];
        #pragma unroll
        for (int kt = 0; kt < 2; ++kt) {
            floatx16 p;
            #pragma unroll
            for (int r = 0; r < 16; ++r) p[r] = __builtin_amdgcn_exp2f(st[kt][r]);
            #pragma unroll
            for (int r = 0; r < 16; r += 4)
                l_r += (p[r] + p[r + 1]) + (p[r + 2] + p[r + 3]);
            U4S8 u0, u1;
            u0.u.x = pack2f(p[0], p[1]);
            u0.u.y = pack2f(p[2], p[3]);
            u0.u.z = pack2f(p[4], p[5]);
            u0.u.w = pack2f(p[6], p[7]);
            u1.u.x = pack2f(p[8], p[9]);
            u1.u.y = pack2f(p[10], p[11]);
            u1.u.z = pack2f(p[12], p[13]);
            u1.u.w = pack2f(p[14], p[15]);
            pf[2 * kt + 0] = u0.s;
            pf[2 * kt + 1] = u1.s;
        }

        // O^T[d][q] += V^T(A) x P(B)
        #pragma unroll
        for (int dt = 0; dt < 2; ++dt) {
            #pragma unroll
            for (int ks = 0; ks < 4; ++ks) {
                const int c8 = ks * 2 + half;
                const short8 vf = *(const short8*)&Vc[(dt * 32 + l31) * DK + ((c8 ^ swl) << 3)];
                o[dt] = __builtin_amdgcn_mfma_f32_32x32x16_bf16(vf, pf[ks], o[dt], 0, 0, 0);
            }
        }
    };

    for (int it = 0; it < S_LEN / 64; it += 2) {
        body(it, Ks0, Vs0, Ks1, Vs1);
        body(it + 1, Ks1, Vs1, Ks0, Vs0);
    }

    // lane's q = l31 throughout; halves cover disjoint kv
    l_r += __shfl_xor(l_r, 32);
    const float inv = 1.0f / l_r;
    const int s = q0 + w * 32 + l31;
    ushort_t* Xrow = X + ((size_t)b * S_LEN + s) * DM + h * DK;
    #pragma unroll
    for (int dt = 0; dt < 2; ++dt)
        #pragma unroll
        for (int g = 0; g < 4; ++g) {
            const float a0 = o[dt][4 * g + 0] * inv;
            const float a1 = o[dt][4 * g + 1] * inv;
            const float a2 = o[dt][4 * g + 2] * inv;
            const float a3 = o[dt][4 * g + 3] * inv;
            uint2 pk;
            pk.x = pack2(a0, a1);
            pk.y = pack2(a2, a3);
            *(uint2*)&Xrow[dt * 32 + 8 * g + 4 * half] = pk;
        }
}

// ---------------- launch ----------------------------------------------------
extern "C" void kernel_launch(void* const* d_in, const int* in_sizes, int n_in,
                              void* d_out, int out_size, void* d_ws, size_t ws_size,
                              hipStream_t stream) {
    const float* q = (const float*)d_in[0];
    const float* k = (const float*)d_in[1];
    const float* v = (const float*)d_in[2];
    const int* mask = (const int*)d_in[3];
    const float* Wq = (const float*)d_in[4];
    const float* bq = (const float*)d_in[5];
    const float* Wk = (const float*)d_in[6];
    const float* bk = (const float*)d_in[7];
    const float* Wv = (const float*)d_in[8];
    const float* bv = (const float*)d_in[9];
    const float* Wo = (const float*)d_in[10];
    const float* bo = (const float*)d_in[11];
    float* out = (float*)d_out;

    const size_t ME = (size_t)2 * S_LEN * DM;
    const size_t WE = (size_t)DM * DM;
    ushort_t* Qb = (ushort_t*)d_ws;
    ushort_t* Kb = Qb + ME;
    ushort_t* Vb = Kb + ME;
    ushort_t* VTb = Vb + ME;
    ushort_t* Xb = VTb + ME;
    ushort_t* Wqt = Xb + ME;
    ushort_t* Wkt = Wqt + WE;
    ushort_t* Wvt = Wkt + WE;
    ushort_t* Wot = Wvt + WE;
    // bf16 copies of q,k,v aliased into regions dead until later stages:
    ushort_t* Qa = Xb;                 // Xb written only by attn
    ushort_t* Ka = VTb;                // VTb written only by vtrans
    ushort_t* Va = (ushort_t*)d_out;   // out written only by gemm2 (last)

    prep_kernel<<<dim3(2304 + 9216), 256, 0, stream>>>(
        Wq, Wk, Wv, Wo, Wqt, Wkt, Wvt, Wot, q, k, v, Qa, Ka, Va);

    GemmArgs g1;
    g1.A[0] = Qa;  g1.A[1] = Ka;  g1.A[2] = Va;
    g1.Wt[0] = Wqt; g1.Wt[1] = Wkt; g1.Wt[2] = Wvt;
    g1.bias[0] = bq; g1.bias[1] = bk; g1.bias[2] = bv;
    g1.C[0] = Qb;  g1.C[1] = Kb;  g1.C[2] = Vb;
    g1.scale[0] = 0.125f * LOG2E;
    g1.scale[1] = 1.0f; g1.scale[2] = 1.0f;
    gemm_kernel<0><<<dim3((2 * S_LEN) / 128, DM / 128, 3), 256, 0, stream>>>(g1);

    vtrans_kernel<<<dim3(S_LEN / 64, 2 * NH), 256, 0, stream>>>(Vb, VTb);

    attn_kernel<<<dim3(768), 256, 0, stream>>>(Qb, Kb, VTb, mask, Xb);

    GemmArgs g2;
    g2.A[0] = Xb;  g2.A[1] = Xb;  g2.A[2] = Xb;
    g2.Wt[0] = Wot; g2.Wt[1] = Wot; g2.Wt[2] = Wot;
    g2.bias[0] = bo; g2.bias[1] = bo; g2.bias[2] = bo;
    g2.C[0] = out; g2.C[1] = out; g2.C[2] = out;
    g2.scale[0] = 1.0f; g2.scale[1] = 1.0f; g2.scale[2] = 1.0f;
    gemm_kernel<1><<<dim3((2 * S_LEN) / 128, DM / 128, 1), 256, 0, stream>>>(g2);
}